// Round 1
// baseline (683.720 us; speedup 1.0000x reference)
//
#include <hip/hip_runtime.h>

#define NTOK 49
#define DIM 192
#define HEADS 6
#define NWIN 64
#define NBLK 4096

typedef unsigned short u16;
typedef short bf16x8 __attribute__((ext_vector_type(8)));
typedef unsigned short u16x4 __attribute__((ext_vector_type(4)));
typedef unsigned short u16x8 __attribute__((ext_vector_type(8)));
typedef float f32x4 __attribute__((ext_vector_type(4)));

#define QKVW_ELEMS (3 * DIM * DIM)   // 110592
#define PROJW_ELEMS (DIM * DIM)      // 36864

// ---------------- split-path workspace layout (bytes) ----------------
//  [0, 294912)             bf16 weights (qkv 110592 u16 + proj 36864 u16)
//  [294912, 332544)        rope table [H][49][8] float4 = (cos a0,sin a0,cos a1,sin a1)
//  [332544, +77070336)     Q bf16 [4096][49][192]
//  [..,     +77070336)     K bf16 [4096][49][192]
//  V^T bf16 [192][64] per block lives inside the block's own d_out slot
//  (24576 B used of the 37632 B output slot -> block-private, race-free).
#define TB_OFF_BYTES ((QKVW_ELEMS + PROJW_ELEMS) * 2)        // 294912
#define TB_QUADS     (HEADS * NTOK * 8)                       // 2352 float4
#define QG_OFF_U16   ((TB_OFF_BYTES + TB_QUADS * 16) / 2)     // 166272
#define QG_ELEMS     (NBLK * NTOK * DIM)                      // 38535168
#define KG_OFF_U16   (QG_OFF_U16 + QG_ELEMS)
#define WS_NEEDED_BYTES (((size_t)KG_OFF_U16 + (size_t)QG_ELEMS) * 2)  // 154473216

// ---------------- fallback fused-kernel LDS map ----------------
#define Q_OFF    0
#define K_OFF    20000
#define PS_OFF   40000
#define VT_OFF   49216
#define XS_OFF   49216
#define OS_OFF   20000
#define MK_OFF   76864
#define LDS_TOTAL 81764

__device__ __forceinline__ float bf2f(u16 u) {
    union { unsigned int i; float f; } x; x.i = ((unsigned int)u) << 16; return x.f;
}
__device__ __forceinline__ u16 f2bf(float f) {
    union { float f; unsigned int u; } x; x.f = f;
    unsigned int u = x.u;
    u += 0x7fffu + ((u >> 16) & 1u);   // RNE
    return (u16)(u >> 16);
}

// fp32 -> bf16 weight pre-convert into workspace
extern "C" __global__ void __launch_bounds__(256)
convert_weights(const float* __restrict__ qkv_w, const float* __restrict__ proj_w,
                u16* __restrict__ ws) {
    int i = (blockIdx.x * 256 + threadIdx.x) * 4;
    if (i >= QKVW_ELEMS + PROJW_ELEMS) return;
    const float* s = (i < QKVW_ELEMS) ? (qkv_w + i) : (proj_w + (i - QKVW_ELEMS));
    float4 v = *(const float4*)s;
    ushort4 o;
    o.x = f2bf(v.x); o.y = f2bf(v.y); o.z = f2bf(v.z); o.w = f2bf(v.w);
    *(ushort4*)(ws + i) = o;
}

// rope cos/sin table: one float4 per (h, t, channel-pair-pair)
extern "C" __global__ void __launch_bounds__(256)
rope_table(const float* __restrict__ rfreq, float* __restrict__ tb) {
    int i = blockIdx.x * 256 + threadIdx.x;
    if (i >= TB_QUADS) return;
    int h = i / (NTOK * 8);
    int r = i % (NTOK * 8);
    int t = r >> 3;
    int p0 = (r & 7) * 2;
    float tx = (float)(t % 7), ty = (float)(t / 7);
    float a0 = tx * rfreq[h * 16 + p0]     + ty * rfreq[96 + h * 16 + p0];
    float a1 = tx * rfreq[h * 16 + p0 + 1] + ty * rfreq[96 + h * 16 + p0 + 1];
    float4 o;
    o.x = cosf(a0); o.y = sinf(a0);
    o.z = cosf(a1); o.w = sinf(a1);
    ((float4*)tb)[i] = o;
}

// ==================== kernel 1: QKV GEMM + bias + RoPE ====================
// LDS: qs [0,20000) [50][200]u16 ; ks [20000,40000) ; xs [64][200]u16 overlays
// [14400,40000) (dead after the B-fragment hoist). 40000 B total.
extern "C" __global__ void __launch_bounds__(256, 3)
qkv_rope(const float* __restrict__ x, const u16* __restrict__ wsq,
         const float* __restrict__ qkv_b, const float* __restrict__ tb,
         u16* __restrict__ qg, u16* __restrict__ kg, u16* __restrict__ vg)
{
    __shared__ __align__(16) char smem[40000];
    u16* qs = (u16*)(smem);
    u16* ks = (u16*)(smem + 20000);
    u16* xs = (u16*)(smem + 14400);

    const int tid  = threadIdx.x;
    const int wave = tid >> 6;
    const int lane = tid & 63;
    const int ln   = lane & 15;
    const int quad = lane >> 4;
    const int blk  = blockIdx.x;
    const float* xg = x + (long)blk * NTOK * DIM;
    const f32x4 fzero = {0.f, 0.f, 0.f, 0.f};

    // stage x -> xs (bf16), zero pad token rows 49..63
    for (int i = tid; i < NTOK * 48; i += 256) {
        int r = i / 48, c = (i % 48) * 4;
        float4 v = *(const float4*)(xg + r * DIM + c);
        u16x4 o = { f2bf(v.x), f2bf(v.y), f2bf(v.z), f2bf(v.w) };
        *(u16x4*)(xs + r * 200 + c) = o;
    }
    {
        u16x8 zz = {0,0,0,0,0,0,0,0};
        for (int i = tid; i < 15 * 25; i += 256) {
            int r = 49 + i / 25, c = (i % 25) * 8;
            *(u16x8*)(xs + r * 200 + c) = zz;
        }
    }
    __syncthreads();

    // hoist QKV B-fragments (x tokens) into registers; xs dead afterwards
    bf16x8 bfrag[6][4];
    #pragma unroll
    for (int kk = 0; kk < 6; kk++)
        #pragma unroll
        for (int nt = 0; nt < 4; nt++)
            bfrag[kk][nt] = *(const bf16x8*)(xs + (nt * 16 + ln) * 200 + kk * 32 + quad * 8);
    __syncthreads();

    const float scale = 0.17677669529663687f;  // 32^-0.5
    u16* vb = vg + (long)blk * (NTOK * DIM * 2);   // V^T [192][64] in own out-slot

    for (int jt = wave; jt < 36; jt += 4) {
        bf16x8 af[6];
        const u16* wr = wsq + (jt * 16 + ln) * DIM + quad * 8;
        #pragma unroll
        for (int kk = 0; kk < 6; kk++) af[kk] = *(const bf16x8*)(wr + kk * 32);
        f32x4 acc[4];
        #pragma unroll
        for (int nt = 0; nt < 4; nt++) acc[nt] = fzero;
        #pragma unroll
        for (int kk = 0; kk < 6; kk++)
            #pragma unroll
            for (int nt = 0; nt < 4; nt++)
                acc[nt] = __builtin_amdgcn_mfma_f32_16x16x32_bf16(af[kk], bfrag[kk][nt], acc[nt], 0, 0, 0);

        int j0 = jt * 16 + quad * 4;
        int qkvi = j0 / DIM;                // wave-uniform: 0=q 1=k 2=v
        int c0 = j0 % DIM;
        int h  = c0 >> 5;
        int p0 = (c0 & 31) >> 1;
        float b0 = qkv_b[j0],   b1 = qkv_b[j0+1];
        float b2 = qkv_b[j0+2], b3 = qkv_b[j0+3];
        #pragma unroll
        for (int nt = 0; nt < 4; nt++) {
            int t = nt * 16 + ln;           // token
            float v0 = acc[nt][0] + b0;
            float v1 = acc[nt][1] + b1;
            float v2 = acc[nt][2] + b2;
            float v3 = acc[nt][3] + b3;
            if (qkvi < 2) {
                if (t < NTOK) {
                    float4 tv = ((const float4*)tb)[(h * NTOK + t) * 8 + (p0 >> 1)];
                    float r0 = v0 * tv.x - v1 * tv.y;
                    float i0 = v0 * tv.y + v1 * tv.x;
                    float r1 = v2 * tv.z - v3 * tv.w;
                    float i1 = v2 * tv.w + v3 * tv.z;
                    if (qkvi == 0) { r0 *= scale; i0 *= scale; r1 *= scale; i1 *= scale; }
                    u16x4 pk = { f2bf(r0), f2bf(i0), f2bf(r1), f2bf(i1) };
                    *(u16x4*)((qkvi == 0 ? qs : ks) + t * 200 + c0) = pk;
                }
            } else {
                float w0 = (t < NTOK) ? v0 : 0.f;
                float w1 = (t < NTOK) ? v1 : 0.f;
                float w2 = (t < NTOK) ? v2 : 0.f;
                float w3 = (t < NTOK) ? v3 : 0.f;
                vb[(c0+0)*64 + t] = f2bf(w0);
                vb[(c0+1)*64 + t] = f2bf(w1);
                vb[(c0+2)*64 + t] = f2bf(w2);
                vb[(c0+3)*64 + t] = f2bf(w3);
            }
        }
    }
    __syncthreads();

    // coalesced store q,k -> global [49][192]
    u16* qgb = qg + (long)blk * (NTOK * DIM);
    u16* kgb = kg + (long)blk * (NTOK * DIM);
    for (int i = tid; i < 2 * NTOK * 24; i += 256) {
        int isk = i >= NTOK * 24;
        int j = isk ? i - NTOK * 24 : i;
        int r = j / 24, c = (j % 24) * 8;
        u16x8 vv = *(const u16x8*)((isk ? ks : qs) + r * 200 + c);
        *(u16x8*)((isk ? kgb : qgb) + r * DIM + c) = vv;
    }
}

// ==================== kernel 2: attention + proj ====================
// LDS: ao [0,20000) [50][200]u16 ; ps [20000,29216) [64][72]u16 ;
//      mk [29216,34116) [49][50]u16.  34128 B -> 4 blocks/CU.
extern "C" __global__ void __launch_bounds__(256, 4)
attn_proj(const float* __restrict__ mask, const u16* __restrict__ qg,
          const u16* __restrict__ kg, const u16* __restrict__ wsp,
          const float* __restrict__ proj_b, float* __restrict__ out)
{
    __shared__ __align__(16) char smem[34128];
    u16* ao = (u16*)(smem);
    u16* ps = (u16*)(smem + 20000);
    u16* mk = (u16*)(smem + 29216);

    const int tid  = threadIdx.x;
    const int wave = tid >> 6;
    const int lane = tid & 63;
    const int ln   = lane & 15;
    const int quad = lane >> 4;
    const int blk  = blockIdx.x;
    const int widx = blk & (NWIN - 1);
    const f32x4 fzero = {0.f, 0.f, 0.f, 0.f};

    // stage mask -> LDS bf16 ; zero ao pad row 49
    for (int i = tid; i < NTOK * NTOK; i += 256) {
        int n = i / NTOK, m = i % NTOK;
        mk[n * 50 + m] = f2bf(mask[widx * (NTOK * NTOK) + i]);
    }
    if (tid < 25) {
        u16x8 zz = {0,0,0,0,0,0,0,0};
        *(u16x8*)(ao + 49 * 200 + tid * 8) = zz;
    }
    __syncthreads();

    const u16* qb = qg + (long)blk * (NTOK * DIM);
    const u16* kb = kg + (long)blk * (NTOK * DIM);
    const u16* vb = (const u16*)out + (long)blk * (NTOK * DIM * 2);  // V^T [192][64]

    int qrow = wave * 16 + ln; if (qrow > 48) qrow = 48;   // clamp: pad rows read real data, outputs discarded
    for (int h = 0; h < HEADS; h++) {
        f32x4 s4[4];
        bf16x8 aq = *(const bf16x8*)(qb + qrow * DIM + h * 32 + quad * 8);
        #pragma unroll
        for (int nt = 0; nt < 4; nt++) {
            int krow = nt * 16 + ln; if (krow > 48) krow = 48;
            bf16x8 bk = *(const bf16x8*)(kb + krow * DIM + h * 32 + quad * 8);
            s4[nt] = __builtin_amdgcn_mfma_f32_16x16x32_bf16(aq, bk, fzero, 0, 0, 0);
        }
        #pragma unroll
        for (int nt = 0; nt < 4; nt++) {
            int m = nt * 16 + ln;
            #pragma unroll
            for (int r = 0; r < 4; r++) {
                int n = wave * 16 + quad * 4 + r;
                if (m >= NTOK) s4[nt][r] = -1e30f;
                else if (n < NTOK) s4[nt][r] += bf2f(mk[n * 50 + m]);
            }
        }
        float mx[4], sm[4], rs[4];
        #pragma unroll
        for (int r = 0; r < 4; r++) {
            float v = fmaxf(fmaxf(s4[0][r], s4[1][r]), fmaxf(s4[2][r], s4[3][r]));
            #pragma unroll
            for (int d = 1; d < 16; d <<= 1) v = fmaxf(v, __shfl_xor(v, d));
            mx[r] = v; sm[r] = 0.f;
        }
        #pragma unroll
        for (int nt = 0; nt < 4; nt++) {
            int m = nt * 16 + ln;
            #pragma unroll
            for (int r = 0; r < 4; r++) {
                float e = __expf(s4[nt][r] - mx[r]);
                sm[r] += e;
                ps[(wave * 16 + quad * 4 + r) * 72 + m] = f2bf(e);
            }
        }
        #pragma unroll
        for (int r = 0; r < 4; r++) {
            float v = sm[r];
            #pragma unroll
            for (int d = 1; d < 16; d <<= 1) v += __shfl_xor(v, d);
            rs[r] = 1.0f / v;
        }
        f32x4 o0 = fzero, o1 = fzero;
        #pragma unroll
        for (int kk = 0; kk < 2; kk++) {
            bf16x8 ap  = *(const bf16x8*)(ps + (wave * 16 + ln) * 72 + kk * 32 + quad * 8);
            bf16x8 bv0 = *(const bf16x8*)(vb + (h * 32 + ln) * 64      + kk * 32 + quad * 8);
            bf16x8 bv1 = *(const bf16x8*)(vb + (h * 32 + 16 + ln) * 64 + kk * 32 + quad * 8);
            o0 = __builtin_amdgcn_mfma_f32_16x16x32_bf16(ap, bv0, o0, 0, 0, 0);
            o1 = __builtin_amdgcn_mfma_f32_16x16x32_bf16(ap, bv1, o1, 0, 0, 0);
        }
        #pragma unroll
        for (int r = 0; r < 4; r++) {
            int t = wave * 16 + quad * 4 + r;
            if (t < NTOK) {
                ao[t * 200 + h * 32 + ln]      = f2bf(o0[r] * rs[r]);
                ao[t * 200 + h * 32 + 16 + ln] = f2bf(o1[r] * rs[r]);
            }
        }
    }
    __syncthreads();   // all V^T reads done before out stores overwrite the slot

    // proj GEMM, direct global stores (no os staging)
    bf16x8 aa[6];
    int arow = wave * 16 + ln; if (arow > NTOK) arow = NTOK;   // row 49 is zeroed
    #pragma unroll
    for (int kk = 0; kk < 6; kk++)
        aa[kk] = *(const bf16x8*)(ao + arow * 200 + kk * 32 + quad * 8);
    float* ob = out + (long)blk * (NTOK * DIM);
    for (int nt = 0; nt < 12; nt++) {
        const u16* wp = wsp + (nt * 16 + ln) * DIM + quad * 8;
        f32x4 p4 = fzero;
        #pragma unroll
        for (int kk = 0; kk < 6; kk++) {
            bf16x8 bw = *(const bf16x8*)(wp + kk * 32);
            p4 = __builtin_amdgcn_mfma_f32_16x16x32_bf16(aa[kk], bw, p4, 0, 0, 0);
        }
        float bb = proj_b[nt * 16 + ln];
        #pragma unroll
        for (int r = 0; r < 4; r++) {
            int t = wave * 16 + quad * 4 + r;
            if (t < NTOK) ob[t * DIM + nt * 16 + ln] = p4[r] + bb;
        }
    }
}

// ==================== fallback: original fused kernel ====================
extern "C" __global__ void __launch_bounds__(256, 2)
fused_win_attn(const float* __restrict__ x, const float* __restrict__ mask,
               const u16* __restrict__ wsq, const float* __restrict__ qkv_b,
               const u16* __restrict__ wsp, const float* __restrict__ proj_b,
               const float* __restrict__ rfreq, float* __restrict__ out)
{
    extern __shared__ __align__(16) char smem[];
    u16* qsm = (u16*)(smem + Q_OFF);
    u16* ksm = (u16*)(smem + K_OFF);
    u16* ps  = (u16*)(smem + PS_OFF);
    u16* vt  = (u16*)(smem + VT_OFF);
    u16* xs  = (u16*)(smem + XS_OFF);
    float* os = (float*)(smem + OS_OFF);
    u16* ao  = (u16*)(smem + Q_OFF);
    u16* mk  = (u16*)(smem + MK_OFF);

    const int tid  = threadIdx.x;
    const int wave = tid >> 6;
    const int lane = tid & 63;
    const int ln   = lane & 15;
    const int quad = lane >> 4;
    const int blk  = blockIdx.x;
    const int widx = blk & (NWIN - 1);
    const float* xg = x + (long)blk * NTOK * DIM;

    const f32x4 fzero = {0.f, 0.f, 0.f, 0.f};

    for (int i = tid; i < NTOK * 48; i += 256) {
        int r = i / 48, c = (i % 48) * 4;
        float4 v = *(const float4*)(xg + r * DIM + c);
        u16x4 o = { f2bf(v.x), f2bf(v.y), f2bf(v.z), f2bf(v.w) };
        *(u16x4*)(xs + r * 200 + c) = o;
    }
    {
        u16x8 zz = {0,0,0,0,0,0,0,0};
        for (int i = tid; i < 15 * 25; i += 256) {
            int r = 49 + i / 25, c = (i % 25) * 8;
            *(u16x8*)(xs + r * 200 + c) = zz;
        }
        if (tid < 50) {
            int c = (tid % 25) * 8;
            u16* base = (tid < 25) ? qsm : ksm;
            *(u16x8*)(base + 49 * 200 + c) = zz;
        }
    }
    for (int i = tid; i < NTOK * NTOK; i += 256) {
        int n = i / NTOK, m = i % NTOK;
        mk[n * 50 + m] = f2bf(mask[widx * (NTOK * NTOK) + i]);
    }
    __syncthreads();

    bf16x8 bfrag[6][4];
    #pragma unroll
    for (int kk = 0; kk < 6; kk++)
        #pragma unroll
        for (int nt = 0; nt < 4; nt++)
            bfrag[kk][nt] = *(const bf16x8*)(xs + (nt * 16 + ln) * 200 + kk * 32 + quad * 8);
    __syncthreads();

    const float scale = 0.17677669529663687f;
    for (int jt = wave; jt < 36; jt += 4) {
        bf16x8 af[6];
        const u16* wr = wsq + (jt * 16 + ln) * DIM + quad * 8;
        #pragma unroll
        for (int kk = 0; kk < 6; kk++) af[kk] = *(const bf16x8*)(wr + kk * 32);
        f32x4 acc[4];
        #pragma unroll
        for (int nt = 0; nt < 4; nt++) acc[nt] = fzero;
        #pragma unroll
        for (int kk = 0; kk < 6; kk++)
            #pragma unroll
            for (int nt = 0; nt < 4; nt++)
                acc[nt] = __builtin_amdgcn_mfma_f32_16x16x32_bf16(af[kk], bfrag[kk][nt], acc[nt], 0, 0, 0);

        int j0 = jt * 16 + quad * 4;
        int qkvi = j0 / DIM;
        int c0 = j0 % DIM;
        int h  = c0 >> 5;
        int p0 = (c0 & 31) >> 1;
        float b0 = qkv_b[j0],   b1 = qkv_b[j0+1];
        float b2 = qkv_b[j0+2], b3 = qkv_b[j0+3];
        float fx0 = rfreq[h*16+p0],   fy0 = rfreq[96+h*16+p0];
        float fx1 = rfreq[h*16+p0+1], fy1 = rfreq[96+h*16+p0+1];
        #pragma unroll
        for (int nt = 0; nt < 4; nt++) {
            int t = nt * 16 + ln;
            float v0 = acc[nt][0] + b0;
            float v1 = acc[nt][1] + b1;
            float v2 = acc[nt][2] + b2;
            float v3 = acc[nt][3] + b3;
            if (qkvi < 2) {
                float tx = (float)(t % 7), ty = (float)(t / 7);
                float a0 = tx * fx0 + ty * fy0;
                float a1 = tx * fx1 + ty * fy1;
                float s0, c0s, s1, c1s;
                __sincosf(a0, &s0, &c0s);
                __sincosf(a1, &s1, &c1s);
                float r0 = v0 * c0s - v1 * s0;
                float i0 = v0 * s0  + v1 * c0s;
                float r1 = v2 * c1s - v3 * s1;
                float i1 = v2 * s1  + v3 * c1s;
                if (qkvi == 0) { r0 *= scale; i0 *= scale; r1 *= scale; i1 *= scale; }
                if (t < NTOK) {
                    u16x4 pk = { f2bf(r0), f2bf(i0), f2bf(r1), f2bf(i1) };
                    u16* dst = (qkvi == 0 ? qsm : ksm) + t * 200 + c0;
                    *(u16x4*)dst = pk;
                }
            } else {
                float w0 = (t < NTOK) ? v0 : 0.f;
                float w1 = (t < NTOK) ? v1 : 0.f;
                float w2 = (t < NTOK) ? v2 : 0.f;
                float w3 = (t < NTOK) ? v3 : 0.f;
                vt[(c0+0)*72 + t] = f2bf(w0);
                vt[(c0+1)*72 + t] = f2bf(w1);
                vt[(c0+2)*72 + t] = f2bf(w2);
                vt[(c0+3)*72 + t] = f2bf(w3);
            }
        }
    }
    __syncthreads();

    int qrow = wave * 16 + ln; if (qrow > NTOK) qrow = NTOK;
    for (int h = 0; h < HEADS; h++) {
        f32x4 s4[4];
        bf16x8 aq = *(const bf16x8*)(qsm + qrow * 200 + h * 32 + quad * 8);
        #pragma unroll
        for (int nt = 0; nt < 4; nt++) {
            int krow = nt * 16 + ln; if (krow > NTOK) krow = NTOK;
            bf16x8 bk = *(const bf16x8*)(ksm + krow * 200 + h * 32 + quad * 8);
            s4[nt] = __builtin_amdgcn_mfma_f32_16x16x32_bf16(aq, bk, fzero, 0, 0, 0);
        }
        #pragma unroll
        for (int nt = 0; nt < 4; nt++) {
            int m = nt * 16 + ln;
            #pragma unroll
            for (int r = 0; r < 4; r++) {
                int n = wave * 16 + quad * 4 + r;
                if (m >= NTOK) s4[nt][r] = -1e30f;
                else if (n < NTOK) s4[nt][r] += bf2f(mk[n * 50 + m]);
            }
        }
        float mx[4], sm[4], rs[4];
        #pragma unroll
        for (int r = 0; r < 4; r++) {
            float v = fmaxf(fmaxf(s4[0][r], s4[1][r]), fmaxf(s4[2][r], s4[3][r]));
            #pragma unroll
            for (int d = 1; d < 16; d <<= 1) v = fmaxf(v, __shfl_xor(v, d));
            mx[r] = v; sm[r] = 0.f;
        }
        #pragma unroll
        for (int nt = 0; nt < 4; nt++) {
            int m = nt * 16 + ln;
            #pragma unroll
            for (int r = 0; r < 4; r++) {
                float e = __expf(s4[nt][r] - mx[r]);
                sm[r] += e;
                ps[(wave * 16 + quad * 4 + r) * 72 + m] = f2bf(e);
            }
        }
        #pragma unroll
        for (int r = 0; r < 4; r++) {
            float v = sm[r];
            #pragma unroll
            for (int d = 1; d < 16; d <<= 1) v += __shfl_xor(v, d);
            rs[r] = 1.0f / v;
        }
        f32x4 o0 = fzero, o1 = fzero;
        #pragma unroll
        for (int kk = 0; kk < 2; kk++) {
            bf16x8 ap  = *(const bf16x8*)(ps + (wave * 16 + ln) * 72 + kk * 32 + quad * 8);
            bf16x8 bv0 = *(const bf16x8*)(vt + (h * 32 + ln) * 72      + kk * 32 + quad * 8);
            bf16x8 bv1 = *(const bf16x8*)(vt + (h * 32 + 16 + ln) * 72 + kk * 32 + quad * 8);
            o0 = __builtin_amdgcn_mfma_f32_16x16x32_bf16(ap, bv0, o0, 0, 0, 0);
            o1 = __builtin_amdgcn_mfma_f32_16x16x32_bf16(ap, bv1, o1, 0, 0, 0);
        }
        #pragma unroll
        for (int r = 0; r < 4; r++) {
            int t = wave * 16 + quad * 4 + r;
            if (t < NTOK) {
                ao[t * 200 + h * 32 + ln]      = f2bf(o0[r] * rs[r]);
                ao[t * 200 + h * 32 + 16 + ln] = f2bf(o1[r] * rs[r]);
            }
        }
    }
    __syncthreads();

    bf16x8 aa[6];
    int arow = wave * 16 + ln; if (arow > NTOK) arow = NTOK;
    #pragma unroll
    for (int kk = 0; kk < 6; kk++)
        aa[kk] = *(const bf16x8*)(ao + arow * 200 + kk * 32 + quad * 8);
    for (int nt = 0; nt < 12; nt++) {
        const u16* wp = wsp + (nt * 16 + ln) * DIM + quad * 8;
        f32x4 p4 = fzero;
        #pragma unroll
        for (int kk = 0; kk < 6; kk++) {
            bf16x8 bw = *(const bf16x8*)(wp + kk * 32);
            p4 = __builtin_amdgcn_mfma_f32_16x16x32_bf16(aa[kk], bw, p4, 0, 0, 0);
        }
        float bb = proj_b[nt * 16 + ln];
        #pragma unroll
        for (int r = 0; r < 4; r++) {
            int t = wave * 16 + quad * 4 + r;
            os[t * 196 + nt * 16 + ln] = p4[r] + bb;
        }
    }
    __syncthreads();

    float* og = out + (long)blk * NTOK * DIM;
    for (int i = tid; i < NTOK * 48; i += 256) {
        int r = i / 48, c = (i % 48) * 4;
        *(float4*)(og + r * DIM + c) = *(const float4*)(os + r * 196 + c);
    }
}

extern "C" void kernel_launch(void* const* d_in, const int* in_sizes, int n_in,
                              void* d_out, int out_size, void* d_ws, size_t ws_size,
                              hipStream_t stream) {
    (void)in_sizes; (void)n_in; (void)out_size;
    u16* ws = (u16*)d_ws;
    convert_weights<<<dim3((QKVW_ELEMS + PROJW_ELEMS) / 4 / 256 + 1), dim3(256), 0, stream>>>(
        (const float*)d_in[2], (const float*)d_in[4], ws);
    if (ws_size >= WS_NEEDED_BYTES) {
        float* tb = (float*)((char*)d_ws + TB_OFF_BYTES);
        rope_table<<<dim3((TB_QUADS + 255) / 256), dim3(256), 0, stream>>>(
            (const float*)d_in[6], tb);
        u16* qg = ws + QG_OFF_U16;
        u16* kg = ws + KG_OFF_U16;
        qkv_rope<<<dim3(NBLK), dim3(256), 0, stream>>>(
            (const float*)d_in[0], ws, (const float*)d_in[3], tb, qg, kg, (u16*)d_out);
        attn_proj<<<dim3(NBLK), dim3(256), 0, stream>>>(
            (const float*)d_in[1], qg, kg, ws + QKVW_ELEMS, (const float*)d_in[5],
            (float*)d_out);
    } else {
        hipFuncSetAttribute(reinterpret_cast<const void*>(fused_win_attn),
                            hipFuncAttributeMaxDynamicSharedMemorySize, LDS_TOTAL);
        fused_win_attn<<<dim3(NBLK), dim3(256), LDS_TOTAL, stream>>>(
            (const float*)d_in[0], (const float*)d_in[1],
            ws, (const float*)d_in[3],
            ws + QKVW_ELEMS, (const float*)d_in[5],
            (const float*)d_in[6], (float*)d_out);
    }
}